// Round 4
// baseline (4981.848 us; speedup 1.0000x reference)
//
#include <hip/hip_runtime.h>

// Residual 2-layer LSTM, T=256 B=64 H=1024, fp32 io, bf16 MFMA compute.
//
// R7 = R6 with the flag POLL/STORE line sets made disjoint again.
//
// R5/R6 post-mortem: pointing L6's 128-WG poll storm at flags5[t] -- the
// same 8 LLC lines L5's critical-path flag stores must win -- cost 5 us/step
// (R4 3622us -> R5 4979 / R6 4920; unbundling proved the poll-target change,
// not the per-wave polling, was the culprit). Flag-array discipline:
//   flags5: STORED by L5 (critical window), POLLED only by L5 peers (t-1 lines)
//   flagsO: STORED by L5 (same window, tid0 second store), POLLED only by L6
//   flags6: STORED by L6 (critical window), POLLED only by L6 peers (t-1 lines)
// No polled line is on anyone's critical store path; every array has one
// disjoint poller population.
//
// Kept from R6 (the merged publish window): h5, out5b (= h + prefetched x
// residual, fp32 math) and BOTH flags are published under ONE vmcnt(0) +
// barrier. vs R4 this deletes L5's second drain+barrier and raises the L6
// handoff flag ~2k cycles earlier.
//
// Coherence (one dispatch, no boundary flush):
//  - h5/h6/out5b written with AGENT-scope 4B stores + vmcnt(0) drain before
//    the flag stores. Reader-side cached loads are safe: addresses are
//    virgin within the dispatch (written once agent-scope -> LLC, read after).

#define TT 256
#define BB 64
#define HH 1024
#define GG 128
#define BH (BB * HH)

typedef __attribute__((ext_vector_type(8))) short short8;
typedef __attribute__((ext_vector_type(4))) float float4v;
typedef __attribute__((ext_vector_type(2))) float float2v;

__device__ __forceinline__ unsigned short f2bf(float f) {
  unsigned u = __builtin_bit_cast(unsigned, f);
  u += 0x7fffu + ((u >> 16) & 1u);
  return (unsigned short)(u >> 16);
}
__device__ __forceinline__ float bf2f(unsigned short s) {
  unsigned u = ((unsigned)s) << 16;
  return __builtin_bit_cast(float, u);
}
__device__ __forceinline__ float fexp2(float x) { return __builtin_amdgcn_exp2f(x); }
__device__ __forceinline__ float frcp(float x) { return __builtin_amdgcn_rcpf(x); }
__device__ __forceinline__ float sigm(float x) {
  return frcp(1.0f + fexp2(-1.4426950408889634f * x));
}
__device__ __forceinline__ float tanha(float x) {
  return 1.0f - 2.0f * frcp(1.0f + fexp2(2.8853900817779268f * x));
}

__global__ __launch_bounds__(256, 1) void lstm2_fused(
    const float* __restrict__ x,
    const float* __restrict__ wih5, const float* __restrict__ whh5,
    const float* __restrict__ bih5, const float* __restrict__ bhh5,
    const float* __restrict__ wih6, const float* __restrict__ whh6,
    const float* __restrict__ bih6, const float* __restrict__ bhh6,
    unsigned short* __restrict__ out5b, unsigned short* __restrict__ hbuf5,
    unsigned short* __restrict__ hbuf6, float* __restrict__ out,
    int* __restrict__ flags5, int* __restrict__ flagsO,
    int* __restrict__ flags6) {
  const int role = (int)(blockIdx.x >> 7); // 0 = layer5, 1 = layer6
  const int p = (int)(blockIdx.x & 127);   // column block (8 h-cols)
  const int tid = threadIdx.x;
  const int w = tid >> 6;
  const int lane = tid & 63;
  const int ln = lane & 15;
  const int q = lane >> 4;

  __shared__ float gp[4][BB][35];

  const float* wih = role ? wih6 : wih5;
  const float* whh = role ? whh6 : whh5;
  const float* bih = role ? bih6 : bih5;
  const float* bhh = role ? bhh6 : bhh5;
  unsigned short* hbuf = role ? hbuf6 : hbuf5;

  // ---- persistent weight fragments: this wave covers k in [256w, 256w+256)
  // wf[kk*2+nt]: n = 16*nt+ln, k = 256*w + kk*32 + 8*q + j
  short8 wfx[16], wfh[16];
#pragma unroll
  for (int kk = 0; kk < 8; ++kk) {
#pragma unroll
    for (int nt = 0; nt < 2; ++nt) {
      const int n = 16 * nt + ln;
      const int gidx = (n >> 3) * HH + p * 8 + (n & 7); // gate order i,f,g,o
      const int k0 = 256 * w + kk * 32 + 8 * q;
      const float* sx = wih + (size_t)gidx * HH + k0;
      const float* sh = whh + (size_t)gidx * HH + k0;
      short8 vx, vh;
#pragma unroll
      for (int j = 0; j < 8; ++j) { vx[j] = (short)f2bf(sx[j]); vh[j] = (short)f2bf(sh[j]); }
      wfx[kk * 2 + nt] = vx;
      wfh[kk * 2 + nt] = vh;
    }
  }

  // ---- elementwise state: thread owns (b=lane, cols 2w and 2w+1)
  const int eb = lane;
  const int jj0 = w;
  float bsum[2][4];
#pragma unroll
  for (int s = 0; s < 2; ++s) {
    const int jj = 2 * jj0 + s;
#pragma unroll
    for (int gt = 0; gt < 4; ++gt) {
      const int gidx = gt * HH + p * 8 + jj;
      bsum[s][gt] = bih[gidx] + bhh[gidx];
    }
  }
  float cst[2] = {0.f, 0.f};

  // ---- A-operand offsets
  size_t rh[4];  // blocked bf16 layout [t][col>>3][b][col&7]
  size_t rxf[4]; // fp32 row-major [t][b][h] (layer5 x)
#pragma unroll
  for (int mt = 0; mt < 4; ++mt) {
    rh[mt] = (size_t)(16 * mt + ln) * 8 + (size_t)(256 * w + 8 * q) * 64;
    rxf[mt] = (size_t)(16 * mt + ln) * HH + (size_t)(256 * w + 8 * q);
  }

  for (int t = 0; t < TT; ++t) {
    float4v acc[4][2];
#pragma unroll
    for (int mt = 0; mt < 4; ++mt)
#pragma unroll
      for (int nt = 0; nt < 2; ++nt)
        acc[mt][nt] = (float4v){0.f, 0.f, 0.f, 0.f};

    const size_t tb = (size_t)t * BH;
    const size_t hidx = tb + (size_t)p * 512 + (size_t)eb * 8 + 2 * jj0;
    float2v rres; // layer5 x-residual, prefetched before the publish window

    if (role == 0) {
      // residual prefetch (read-only, no cross-WG dependency; arrives
      // during the x-part, so the publish window never waits on it)
      rres = *(const float2v*)(x + tb + (size_t)eb * HH + p * 8 + 2 * jj0);
      // ---- layer5 x-part: fp32 x, cvt on the fly (no cross-WG dependency;
      // overlaps other WGs' tails -> VALU hides in straggler slack)
      const float* Xb = x + tb;
#pragma unroll
      for (int kk = 0; kk < 8; ++kk) {
        short8 af[4];
#pragma unroll
        for (int mt = 0; mt < 4; ++mt) {
          const float* sx = Xb + rxf[mt] + 32 * kk;
          const float4v a = *(const float4v*)sx;
          const float4v b = *(const float4v*)(sx + 4);
          short8 v;
          v[0] = (short)f2bf(a[0]); v[1] = (short)f2bf(a[1]);
          v[2] = (short)f2bf(a[2]); v[3] = (short)f2bf(a[3]);
          v[4] = (short)f2bf(b[0]); v[5] = (short)f2bf(b[1]);
          v[6] = (short)f2bf(b[2]); v[7] = (short)f2bf(b[3]);
          af[mt] = v;
        }
#pragma unroll
        for (int mt = 0; mt < 4; ++mt) {
          acc[mt][0] = __builtin_amdgcn_mfma_f32_16x16x32_bf16(af[mt], wfx[kk * 2 + 0], acc[mt][0], 0, 0, 0);
          acc[mt][1] = __builtin_amdgcn_mfma_f32_16x16x32_bf16(af[mt], wfx[kk * 2 + 1], acc[mt][1], 0, 0, 0);
        }
      }
      // gate h-part on all 128 layer-5 WGs having published h5[t-1]
      if (t > 0) {
        if (w == 0) {
          int* fl = flags5 + (size_t)(t - 1) * GG;
          for (;;) {
            const int a0 = __hip_atomic_load(fl + lane, __ATOMIC_RELAXED, __HIP_MEMORY_SCOPE_AGENT);
            const int a1 = __hip_atomic_load(fl + 64 + lane, __ATOMIC_RELAXED, __HIP_MEMORY_SCOPE_AGENT);
            if (__all((a0 != 0) & (a1 != 0))) break;
            __builtin_amdgcn_s_sleep(2);
          }
        }
        __builtin_amdgcn_fence(__ATOMIC_ACQUIRE, "workgroup"); // compiler order only
        __syncthreads();
      }
    } else {
      // ---- layer6 gate: out5[t] ready (all 128, via flagsO -- raised in the
      // same publish window as flags5) AND own h6[t-1] ready
      if (w == 0) {
        int* fo = flagsO + (size_t)t * GG;
        int* fh = flags6 + (size_t)(t > 0 ? t - 1 : 0) * GG;
        for (;;) {
          const int a0 = __hip_atomic_load(fo + lane, __ATOMIC_RELAXED, __HIP_MEMORY_SCOPE_AGENT);
          const int a1 = __hip_atomic_load(fo + 64 + lane, __ATOMIC_RELAXED, __HIP_MEMORY_SCOPE_AGENT);
          int ok = (a0 != 0) & (a1 != 0);
          if (t > 0) {
            const int b0 = __hip_atomic_load(fh + lane, __ATOMIC_RELAXED, __HIP_MEMORY_SCOPE_AGENT);
            const int b1 = __hip_atomic_load(fh + 64 + lane, __ATOMIC_RELAXED, __HIP_MEMORY_SCOPE_AGENT);
            ok &= (b0 != 0) & (b1 != 0);
          }
          if (__all(ok)) break;
          __builtin_amdgcn_s_sleep(2);
        }
      }
      __builtin_amdgcn_fence(__ATOMIC_ACQUIRE, "workgroup"); // compiler order only
      __syncthreads();
      // ---- layer6 x-part: out5b blocked bf16 (cached; virgin addrs -> LLC-fresh)
      const unsigned short* Ab = out5b + tb;
#pragma unroll
      for (int kk = 0; kk < 8; ++kk) {
        short8 af[4];
#pragma unroll
        for (int mt = 0; mt < 4; ++mt)
          af[mt] = *(const short8*)(Ab + rh[mt] + (size_t)kk * 2048);
#pragma unroll
        for (int mt = 0; mt < 4; ++mt) {
          acc[mt][0] = __builtin_amdgcn_mfma_f32_16x16x32_bf16(af[mt], wfx[kk * 2 + 0], acc[mt][0], 0, 0, 0);
          acc[mt][1] = __builtin_amdgcn_mfma_f32_16x16x32_bf16(af[mt], wfx[kk * 2 + 1], acc[mt][1], 0, 0, 0);
        }
      }
    }

    // ---- h-part (common; gating already done per-role above)
    if (t > 0) {
      const unsigned short* Hb = hbuf + (size_t)(t - 1) * BH;
#pragma unroll
      for (int kk = 0; kk < 8; ++kk) {
        short8 af[4];
#pragma unroll
        for (int mt = 0; mt < 4; ++mt)
          af[mt] = *(const short8*)(Hb + rh[mt] + (size_t)kk * 2048); // cached
#pragma unroll
        for (int mt = 0; mt < 4; ++mt) {
          acc[mt][0] = __builtin_amdgcn_mfma_f32_16x16x32_bf16(af[mt], wfh[kk * 2 + 0], acc[mt][0], 0, 0, 0);
          acc[mt][1] = __builtin_amdgcn_mfma_f32_16x16x32_bf16(af[mt], wfh[kk * 2 + 1], acc[mt][1], 0, 0, 0);
        }
      }
    }

    // C layout: row m = 16*mt + 4*q + r, col n = 16*nt + ln
#pragma unroll
    for (int mt = 0; mt < 4; ++mt)
#pragma unroll
      for (int nt = 0; nt < 2; ++nt)
#pragma unroll
        for (int r = 0; r < 4; ++r)
          gp[w][16 * mt + 4 * q + r][16 * nt + ln] = acc[mt][nt][r];

    __syncthreads();

    float hv[2];
#pragma unroll
    for (int s = 0; s < 2; ++s) {
      const int jj = 2 * jj0 + s;
      float iv = bsum[s][0], fv = bsum[s][1], gv = bsum[s][2], ov = bsum[s][3];
#pragma unroll
      for (int ww = 0; ww < 4; ++ww) {
        iv += gp[ww][eb][jj];
        fv += gp[ww][eb][8 + jj];
        gv += gp[ww][eb][16 + jj];
        ov += gp[ww][eb][24 + jj];
      }
      const float ig = sigm(iv);
      const float fg = sigm(fv);
      const float gg_ = tanha(gv);
      const float og = sigm(ov);
      const float c = fg * cst[s] + ig * gg_;
      cst[s] = c;
      hv[s] = og * tanha(c);
    }
    const unsigned packed_h = (unsigned)f2bf(hv[0]) | ((unsigned)f2bf(hv[1]) << 16);

    if (role == 0) {
      // publish h5 AND out5 (= h + x residual, fp32 math) in ONE window;
      // raise BOTH flags after one drain (flags5 -> L5 peers, flagsO -> L6)
      __hip_atomic_store((unsigned*)(hbuf5 + hidx), packed_h, __ATOMIC_RELAXED,
                         __HIP_MEMORY_SCOPE_AGENT);
      const float o0 = hv[0] + rres[0];
      const float o1 = hv[1] + rres[1];
      const unsigned po = (unsigned)f2bf(o0) | ((unsigned)f2bf(o1) << 16);
      __hip_atomic_store((unsigned*)(out5b + hidx), po, __ATOMIC_RELAXED,
                         __HIP_MEMORY_SCOPE_AGENT);
      asm volatile("s_waitcnt vmcnt(0)" ::: "memory"); // both stores at coherent point
      __syncthreads();
      if (tid == 0) {
        __hip_atomic_store(flags5 + (size_t)t * GG + p, 1, __ATOMIC_RELAXED,
                           __HIP_MEMORY_SCOPE_AGENT);
        __hip_atomic_store(flagsO + (size_t)t * GG + p, 1, __ATOMIC_RELAXED,
                           __HIP_MEMORY_SCOPE_AGENT);
      }
    } else {
      __hip_atomic_store((unsigned*)(hbuf6 + hidx), packed_h, __ATOMIC_RELAXED,
                         __HIP_MEMORY_SCOPE_AGENT);
      asm volatile("s_waitcnt vmcnt(0)" ::: "memory");
      __syncthreads();
      if (tid == 0)
        __hip_atomic_store(flags6 + (size_t)t * GG + p, 1, __ATOMIC_RELAXED,
                           __HIP_MEMORY_SCOPE_AGENT);
      // ---- final out = h6 + out5 residual (off the inter-WG critical path;
      // cached read of own cols, published under flagsO[t] which this WG
      // already confirmed before its x-part)
      const unsigned rb = *(const unsigned*)(out5b + hidx);
      const float o0 = hv[0] + bf2f((unsigned short)(rb & 0xffff));
      const float o1 = hv[1] + bf2f((unsigned short)(rb >> 16));
      float2v vo; vo[0] = o0; vo[1] = o1;
      *(float2v*)(out + tb + (size_t)eb * HH + p * 8 + 2 * jj0) = vo;
    }
  }
}

extern "C" void kernel_launch(void* const* d_in, const int* in_sizes, int n_in,
                              void* d_out, int out_size, void* d_ws, size_t ws_size,
                              hipStream_t stream) {
  const float* x    = (const float*)d_in[0];
  const float* wih5 = (const float*)d_in[1];
  const float* whh5 = (const float*)d_in[2];
  const float* bih5 = (const float*)d_in[3];
  const float* bhh5 = (const float*)d_in[4];
  const float* wih6 = (const float*)d_in[5];
  const float* whh6 = (const float*)d_in[6];
  const float* bih6 = (const float*)d_in[7];
  const float* bhh6 = (const float*)d_in[8];
  float* out = (float*)d_out;

  // ws (96.4 MB):
  //   [0,32M)   out5b : layer5 output bf16 blocked (layer6 x-input + residual)
  //   [32M,64M) hbuf5 : layer5 h history bf16 blocked
  //   [64M,96M) hbuf6 : layer6 h history bf16 blocked
  //   [96M,+384K) flags5 | flagsO | flags6 (TT*GG ints each)
  char* ws = (char*)d_ws;
  unsigned short* out5b = (unsigned short*)(ws);
  unsigned short* hbuf5 = (unsigned short*)(ws + 33554432);
  unsigned short* hbuf6 = (unsigned short*)(ws + 67108864);
  int* flags            = (int*)(ws + 100663296);
  int* flags5 = flags;
  int* flagsO = flags + TT * GG;
  int* flags6 = flags + 2 * TT * GG;

  hipMemsetAsync(flags, 0, 3 * TT * GG * sizeof(int), stream);

  lstm2_fused<<<dim3(2 * GG), dim3(256), 0, stream>>>(
      x, wih5, whh5, bih5, bhh5, wih6, whh6, bih6, bhh6,
      out5b, hbuf5, hbuf6, out, flags5, flagsO, flags6);
}

// Round 5
// 3627.434 us; speedup vs baseline: 1.3734x; 1.3734x over previous
//
#include <hip/hip_runtime.h>

// Residual 2-layer LSTM, T=256 B=64 H=1024, fp32 io, bf16 MFMA compute.
//
// R8 = EXACT restoration of R4 (the proven 3622us artifact), byte-identical
// modulo comments. R5/R6/R7 unbundling isolated the regression to the merged
// publish window (h5+out5b+flags under one vmcnt(0)): all three variants
// carrying it landed at ~4.95ms regardless of poll topology. Surviving
// mechanism: R4's two-window structure phase-separates the critical h-load
// burst (remote pollers detecting flags5[t]) from the local WG's next x-part
// load storm -- the tail (residual load + out5b store + drain + barrier)
// keeps the fabric quiet for ~2-3k cycles right when the critical loads fly.
// Merging the windows removed that separation: critical h-loads contend with
// 128 WGs' fp32 x-loads + L6's out5b burst => +5us/step idle.
//
// Structure: fused single persistent kernel, 256 WGs x 256 thr, 1 WG/CU.
// WGs [0,128) run layer 5, WGs [128,256) run layer 6, software-pipelined one
// timestep apart: layer6 step t gates on (a) out5[t] published by all 128
// layer-5 WGs (flagsO, raised in L5's TAIL, off the L5 recurrence) and
// (b) its own h6[t-1] flags. Layer 5 never waits on layer 6.
//
// Coherence notes (all within ONE dispatch -> no dispatch-boundary flush):
//  - out5b/h5/h6 written with AGENT-scope 4B stores + vmcnt(0) drain before
//    their flag. Reader-side cached loads are safe: addresses are virgin
//    within the dispatch (written once agent-scope -> LLC, read after).
//  - layer 6 has a DEDICATED hbuf6; layer 5 converts x fp32->bf16 on the fly
//    (same f2bf rounding as a separate cvt pass -> bit-identical numerics).

#define TT 256
#define BB 64
#define HH 1024
#define GG 128
#define BH (BB * HH)

typedef __attribute__((ext_vector_type(8))) short short8;
typedef __attribute__((ext_vector_type(4))) float float4v;
typedef __attribute__((ext_vector_type(2))) float float2v;

__device__ __forceinline__ unsigned short f2bf(float f) {
  unsigned u = __builtin_bit_cast(unsigned, f);
  u += 0x7fffu + ((u >> 16) & 1u);
  return (unsigned short)(u >> 16);
}
__device__ __forceinline__ float bf2f(unsigned short s) {
  unsigned u = ((unsigned)s) << 16;
  return __builtin_bit_cast(float, u);
}
__device__ __forceinline__ float fexp2(float x) { return __builtin_amdgcn_exp2f(x); }
__device__ __forceinline__ float frcp(float x) { return __builtin_amdgcn_rcpf(x); }
__device__ __forceinline__ float sigm(float x) {
  return frcp(1.0f + fexp2(-1.4426950408889634f * x));
}
__device__ __forceinline__ float tanha(float x) {
  return 1.0f - 2.0f * frcp(1.0f + fexp2(2.8853900817779268f * x));
}

__global__ __launch_bounds__(256, 1) void lstm2_fused(
    const float* __restrict__ x,
    const float* __restrict__ wih5, const float* __restrict__ whh5,
    const float* __restrict__ bih5, const float* __restrict__ bhh5,
    const float* __restrict__ wih6, const float* __restrict__ whh6,
    const float* __restrict__ bih6, const float* __restrict__ bhh6,
    unsigned short* __restrict__ out5b, unsigned short* __restrict__ hbuf5,
    unsigned short* __restrict__ hbuf6, float* __restrict__ out,
    int* __restrict__ flags5, int* __restrict__ flagsO,
    int* __restrict__ flags6) {
  const int role = (int)(blockIdx.x >> 7); // 0 = layer5, 1 = layer6
  const int p = (int)(blockIdx.x & 127);   // column block (8 h-cols)
  const int tid = threadIdx.x;
  const int w = tid >> 6;
  const int lane = tid & 63;
  const int ln = lane & 15;
  const int q = lane >> 4;

  __shared__ float gp[4][BB][35];

  const float* wih = role ? wih6 : wih5;
  const float* whh = role ? whh6 : whh5;
  const float* bih = role ? bih6 : bih5;
  const float* bhh = role ? bhh6 : bhh5;
  unsigned short* hbuf = role ? hbuf6 : hbuf5;
  int* hflags = role ? flags6 : flags5;

  // ---- persistent weight fragments: this wave covers k in [256w, 256w+256)
  // wf[kk*2+nt]: n = 16*nt+ln, k = 256*w + kk*32 + 8*q + j
  short8 wfx[16], wfh[16];
#pragma unroll
  for (int kk = 0; kk < 8; ++kk) {
#pragma unroll
    for (int nt = 0; nt < 2; ++nt) {
      const int n = 16 * nt + ln;
      const int gidx = (n >> 3) * HH + p * 8 + (n & 7); // gate order i,f,g,o
      const int k0 = 256 * w + kk * 32 + 8 * q;
      const float* sx = wih + (size_t)gidx * HH + k0;
      const float* sh = whh + (size_t)gidx * HH + k0;
      short8 vx, vh;
#pragma unroll
      for (int j = 0; j < 8; ++j) { vx[j] = (short)f2bf(sx[j]); vh[j] = (short)f2bf(sh[j]); }
      wfx[kk * 2 + nt] = vx;
      wfh[kk * 2 + nt] = vh;
    }
  }

  // ---- elementwise state: thread owns (b=lane, cols 2w and 2w+1)
  const int eb = lane;
  const int jj0 = w;
  float bsum[2][4];
#pragma unroll
  for (int s = 0; s < 2; ++s) {
    const int jj = 2 * jj0 + s;
#pragma unroll
    for (int gt = 0; gt < 4; ++gt) {
      const int gidx = gt * HH + p * 8 + jj;
      bsum[s][gt] = bih[gidx] + bhh[gidx];
    }
  }
  float cst[2] = {0.f, 0.f};

  // ---- A-operand offsets
  size_t rh[4];  // blocked bf16 layout [t][col>>3][b][col&7]
  size_t rxf[4]; // fp32 row-major [t][b][h] (layer5 x)
#pragma unroll
  for (int mt = 0; mt < 4; ++mt) {
    rh[mt] = (size_t)(16 * mt + ln) * 8 + (size_t)(256 * w + 8 * q) * 64;
    rxf[mt] = (size_t)(16 * mt + ln) * HH + (size_t)(256 * w + 8 * q);
  }

  for (int t = 0; t < TT; ++t) {
    float4v acc[4][2];
#pragma unroll
    for (int mt = 0; mt < 4; ++mt)
#pragma unroll
      for (int nt = 0; nt < 2; ++nt)
        acc[mt][nt] = (float4v){0.f, 0.f, 0.f, 0.f};

    if (role == 0) {
      // ---- layer5 x-part: fp32 x, cvt on the fly (no cross-WG dependency;
      // overlaps other WGs' tails -> VALU hides in straggler slack)
      const float* Xb = x + (size_t)t * BH;
#pragma unroll
      for (int kk = 0; kk < 8; ++kk) {
        short8 af[4];
#pragma unroll
        for (int mt = 0; mt < 4; ++mt) {
          const float* sx = Xb + rxf[mt] + 32 * kk;
          const float4v a = *(const float4v*)sx;
          const float4v b = *(const float4v*)(sx + 4);
          short8 v;
          v[0] = (short)f2bf(a[0]); v[1] = (short)f2bf(a[1]);
          v[2] = (short)f2bf(a[2]); v[3] = (short)f2bf(a[3]);
          v[4] = (short)f2bf(b[0]); v[5] = (short)f2bf(b[1]);
          v[6] = (short)f2bf(b[2]); v[7] = (short)f2bf(b[3]);
          af[mt] = v;
        }
#pragma unroll
        for (int mt = 0; mt < 4; ++mt) {
          acc[mt][0] = __builtin_amdgcn_mfma_f32_16x16x32_bf16(af[mt], wfx[kk * 2 + 0], acc[mt][0], 0, 0, 0);
          acc[mt][1] = __builtin_amdgcn_mfma_f32_16x16x32_bf16(af[mt], wfx[kk * 2 + 1], acc[mt][1], 0, 0, 0);
        }
      }
      // gate h-part on all 128 layer-5 WGs having published h5[t-1]
      if (t > 0) {
        if (w == 0) {
          int* fl = flags5 + (size_t)(t - 1) * GG;
          for (;;) {
            const int a0 = __hip_atomic_load(fl + lane, __ATOMIC_RELAXED, __HIP_MEMORY_SCOPE_AGENT);
            const int a1 = __hip_atomic_load(fl + 64 + lane, __ATOMIC_RELAXED, __HIP_MEMORY_SCOPE_AGENT);
            if (__all((a0 != 0) & (a1 != 0))) break;
            __builtin_amdgcn_s_sleep(2);
          }
        }
        __builtin_amdgcn_fence(__ATOMIC_ACQUIRE, "workgroup"); // compiler order only
        __syncthreads();
      }
    } else {
      // ---- layer6 gate: out5[t] ready (all 128) AND own h6[t-1] ready
      if (w == 0) {
        int* fo = flagsO + (size_t)t * GG;
        int* fh = flags6 + (size_t)(t > 0 ? t - 1 : 0) * GG;
        for (;;) {
          const int a0 = __hip_atomic_load(fo + lane, __ATOMIC_RELAXED, __HIP_MEMORY_SCOPE_AGENT);
          const int a1 = __hip_atomic_load(fo + 64 + lane, __ATOMIC_RELAXED, __HIP_MEMORY_SCOPE_AGENT);
          int ok = (a0 != 0) & (a1 != 0);
          if (t > 0) {
            const int b0 = __hip_atomic_load(fh + lane, __ATOMIC_RELAXED, __HIP_MEMORY_SCOPE_AGENT);
            const int b1 = __hip_atomic_load(fh + 64 + lane, __ATOMIC_RELAXED, __HIP_MEMORY_SCOPE_AGENT);
            ok &= (b0 != 0) & (b1 != 0);
          }
          if (__all(ok)) break;
          __builtin_amdgcn_s_sleep(2);
        }
      }
      __builtin_amdgcn_fence(__ATOMIC_ACQUIRE, "workgroup"); // compiler order only
      __syncthreads();
      // ---- layer6 x-part: out5b blocked bf16 (cached; virgin addrs -> LLC-fresh)
      const unsigned short* Ab = out5b + (size_t)t * BH;
#pragma unroll
      for (int kk = 0; kk < 8; ++kk) {
        short8 af[4];
#pragma unroll
        for (int mt = 0; mt < 4; ++mt)
          af[mt] = *(const short8*)(Ab + rh[mt] + (size_t)kk * 2048);
#pragma unroll
        for (int mt = 0; mt < 4; ++mt) {
          acc[mt][0] = __builtin_amdgcn_mfma_f32_16x16x32_bf16(af[mt], wfx[kk * 2 + 0], acc[mt][0], 0, 0, 0);
          acc[mt][1] = __builtin_amdgcn_mfma_f32_16x16x32_bf16(af[mt], wfx[kk * 2 + 1], acc[mt][1], 0, 0, 0);
        }
      }
    }

    // ---- h-part (common; gating already done per-role above)
    if (t > 0) {
      const unsigned short* Hb = hbuf + (size_t)(t - 1) * BH;
#pragma unroll
      for (int kk = 0; kk < 8; ++kk) {
        short8 af[4];
#pragma unroll
        for (int mt = 0; mt < 4; ++mt)
          af[mt] = *(const short8*)(Hb + rh[mt] + (size_t)kk * 2048); // cached
#pragma unroll
        for (int mt = 0; mt < 4; ++mt) {
          acc[mt][0] = __builtin_amdgcn_mfma_f32_16x16x32_bf16(af[mt], wfh[kk * 2 + 0], acc[mt][0], 0, 0, 0);
          acc[mt][1] = __builtin_amdgcn_mfma_f32_16x16x32_bf16(af[mt], wfh[kk * 2 + 1], acc[mt][1], 0, 0, 0);
        }
      }
    }

    // C layout: row m = 16*mt + 4*q + r, col n = 16*nt + ln
#pragma unroll
    for (int mt = 0; mt < 4; ++mt)
#pragma unroll
      for (int nt = 0; nt < 2; ++nt)
#pragma unroll
        for (int r = 0; r < 4; ++r)
          gp[w][16 * mt + 4 * q + r][16 * nt + ln] = acc[mt][nt][r];

    __syncthreads();

    const size_t tb = (size_t)t * BH;
    const size_t hidx = tb + (size_t)p * 512 + (size_t)eb * 8 + 2 * jj0;
    float hv[2];
#pragma unroll
    for (int s = 0; s < 2; ++s) {
      const int jj = 2 * jj0 + s;
      float iv = bsum[s][0], fv = bsum[s][1], gv = bsum[s][2], ov = bsum[s][3];
#pragma unroll
      for (int ww = 0; ww < 4; ++ww) {
        iv += gp[ww][eb][jj];
        fv += gp[ww][eb][8 + jj];
        gv += gp[ww][eb][16 + jj];
        ov += gp[ww][eb][24 + jj];
      }
      const float ig = sigm(iv);
      const float fg = sigm(fv);
      const float gg_ = tanha(gv);
      const float og = sigm(ov);
      const float c = fg * cst[s] + ig * gg_;
      cst[s] = c;
      hv[s] = og * tanha(c);
    }
    // publish h first: packed 2xbf16 agent-scope 4B store -> LLC
    {
      unsigned packed = (unsigned)f2bf(hv[0]) | ((unsigned)f2bf(hv[1]) << 16);
      __hip_atomic_store((unsigned*)(hbuf + hidx), packed, __ATOMIC_RELAXED,
                         __HIP_MEMORY_SCOPE_AGENT);
    }
    asm volatile("s_waitcnt vmcnt(0)" ::: "memory"); // h store at coherent point
    __syncthreads();
    if (tid == 0)
      __hip_atomic_store(hflags + (size_t)t * GG + p, 1, __ATOMIC_RELAXED,
                         __HIP_MEMORY_SCOPE_AGENT);

    // ---- output tail (phase-separation: this tail keeps the local WG off
    // the fabric while remote pollers' critical h-loads complete)
    if (role == 0) {
      // out5 = h5 + x residual; agent-scope store (cross-XCD visible within
      // this dispatch), then raise flagsO for layer6 consumers.
      const float2v r = *(const float2v*)(x + tb + (size_t)eb * HH + p * 8 + 2 * jj0);
      const float o0 = hv[0] + r[0];
      const float o1 = hv[1] + r[1];
      const unsigned po = (unsigned)f2bf(o0) | ((unsigned)f2bf(o1) << 16);
      __hip_atomic_store((unsigned*)(out5b + hidx), po, __ATOMIC_RELAXED,
                         __HIP_MEMORY_SCOPE_AGENT);
      asm volatile("s_waitcnt vmcnt(0)" ::: "memory");
      __syncthreads();
      if (tid == 0)
        __hip_atomic_store(flagsO + (size_t)t * GG + p, 1, __ATOMIC_RELAXED,
                           __HIP_MEMORY_SCOPE_AGENT);
    } else {
      // final out = h6 + out5 residual (cached read of own cols; virgin->valid)
      const unsigned rb = *(const unsigned*)(out5b + hidx);
      const float o0 = hv[0] + bf2f((unsigned short)(rb & 0xffff));
      const float o1 = hv[1] + bf2f((unsigned short)(rb >> 16));
      float2v vo; vo[0] = o0; vo[1] = o1;
      *(float2v*)(out + tb + (size_t)eb * HH + p * 8 + 2 * jj0) = vo;
    }
  }
}

extern "C" void kernel_launch(void* const* d_in, const int* in_sizes, int n_in,
                              void* d_out, int out_size, void* d_ws, size_t ws_size,
                              hipStream_t stream) {
  const float* x    = (const float*)d_in[0];
  const float* wih5 = (const float*)d_in[1];
  const float* whh5 = (const float*)d_in[2];
  const float* bih5 = (const float*)d_in[3];
  const float* bhh5 = (const float*)d_in[4];
  const float* wih6 = (const float*)d_in[5];
  const float* whh6 = (const float*)d_in[6];
  const float* bih6 = (const float*)d_in[7];
  const float* bhh6 = (const float*)d_in[8];
  float* out = (float*)d_out;

  // ws (96.4 MB):
  //   [0,32M)   out5b : layer5 output bf16 blocked (layer6 x-input + residual)
  //   [32M,64M) hbuf5 : layer5 h history bf16 blocked
  //   [64M,96M) hbuf6 : layer6 h history bf16 blocked
  //   [96M,+384K) flags5 | flagsO | flags6 (TT*GG ints each)
  char* ws = (char*)d_ws;
  unsigned short* out5b = (unsigned short*)(ws);
  unsigned short* hbuf5 = (unsigned short*)(ws + 33554432);
  unsigned short* hbuf6 = (unsigned short*)(ws + 67108864);
  int* flags            = (int*)(ws + 100663296);
  int* flags5 = flags;
  int* flagsO = flags + TT * GG;
  int* flags6 = flags + 2 * TT * GG;

  hipMemsetAsync(flags, 0, 3 * TT * GG * sizeof(int), stream);

  lstm2_fused<<<dim3(2 * GG), dim3(256), 0, stream>>>(
      x, wih5, whh5, bih5, bhh5, wih6, whh6, bih6, bhh6,
      out5b, hbuf5, hbuf6, out, flags5, flagsO, flags6);
}

// Round 6
// 3578.304 us; speedup vs baseline: 1.3922x; 1.0137x over previous
//
#include <hip/hip_runtime.h>

// Residual 2-layer LSTM, T=256 B=64 H=1024, fp32 io, bf16 MFMA compute.
//
// R9 = R8 (the reproduced 3.62ms R4 artifact) + XCD-PARTITIONED ROLES.
// Single change: block->XCD placement is round-robin (xcd = bid & 7), so
// role = (xcd >= 4): layer 5 owns XCDs 0-3, layer 6 owns XCDs 4-7
// (p = (bid>>3)*4 + (xcd&3) covers [0,128) per role). Rationale: in R8 every
// XCD hosted 16 L5 + 16 L6 WGs; each WG reads the FULL 64-row A-tiles
// (L5: x[t] 256KB fp32 + h5 128KB; L6: out5b 128KB + h6 128KB) through its
// XCD L2 -> ~10MB/step/XCD of L2 service split across two disjoint working
// sets, with both layers' agent-scope handshake bursts interleaved in the
// same queues. Partitioning gives each XCD one layer's working set, halves
// LLC fan-out per shared line, and unmixes the two layers' critical-path
// loads. NO ordering/flag/window changes (R5-R7 proved R4's publish/tail
// order is load-bearing).
//
// Structure: fused single persistent kernel, 256 WGs x 256 thr, 1 WG/CU.
// Layer6 step t gates on (a) out5[t] published by all 128 layer-5 WGs
// (flagsO, raised in L5's TAIL, off the L5 recurrence) and (b) its own
// h6[t-1] flags. Layer 5 never waits on layer 6.
//
// Coherence notes (all within ONE dispatch -> no dispatch-boundary flush):
//  - out5b/h5/h6 written with AGENT-scope 4B stores + vmcnt(0) drain before
//    their flag. Reader-side cached loads are safe: addresses are virgin
//    within the dispatch (written once agent-scope -> LLC, read after).
//  - layer 6 has a DEDICATED hbuf6; layer 5 converts x fp32->bf16 on the fly
//    (same f2bf rounding as a separate cvt pass -> bit-identical numerics).

#define TT 256
#define BB 64
#define HH 1024
#define GG 128
#define BH (BB * HH)

typedef __attribute__((ext_vector_type(8))) short short8;
typedef __attribute__((ext_vector_type(4))) float float4v;
typedef __attribute__((ext_vector_type(2))) float float2v;

__device__ __forceinline__ unsigned short f2bf(float f) {
  unsigned u = __builtin_bit_cast(unsigned, f);
  u += 0x7fffu + ((u >> 16) & 1u);
  return (unsigned short)(u >> 16);
}
__device__ __forceinline__ float bf2f(unsigned short s) {
  unsigned u = ((unsigned)s) << 16;
  return __builtin_bit_cast(float, u);
}
__device__ __forceinline__ float fexp2(float x) { return __builtin_amdgcn_exp2f(x); }
__device__ __forceinline__ float frcp(float x) { return __builtin_amdgcn_rcpf(x); }
__device__ __forceinline__ float sigm(float x) {
  return frcp(1.0f + fexp2(-1.4426950408889634f * x));
}
__device__ __forceinline__ float tanha(float x) {
  return 1.0f - 2.0f * frcp(1.0f + fexp2(2.8853900817779268f * x));
}

__global__ __launch_bounds__(256, 1) void lstm2_fused(
    const float* __restrict__ x,
    const float* __restrict__ wih5, const float* __restrict__ whh5,
    const float* __restrict__ bih5, const float* __restrict__ bhh5,
    const float* __restrict__ wih6, const float* __restrict__ whh6,
    const float* __restrict__ bih6, const float* __restrict__ bhh6,
    unsigned short* __restrict__ out5b, unsigned short* __restrict__ hbuf5,
    unsigned short* __restrict__ hbuf6, float* __restrict__ out,
    int* __restrict__ flags5, int* __restrict__ flagsO,
    int* __restrict__ flags6) {
  // XCD partition: round-robin placement means xcd = bid & 7. L5 -> XCDs
  // 0-3, L6 -> XCDs 4-7; p enumerates [0,128) within each role.
  const int xcd = (int)(blockIdx.x & 7);
  const int role = (xcd >= 4) ? 1 : 0;            // 0 = layer5, 1 = layer6
  const int p = (int)(blockIdx.x >> 3) * 4 + (xcd & 3); // column block (8 h-cols)
  const int tid = threadIdx.x;
  const int w = tid >> 6;
  const int lane = tid & 63;
  const int ln = lane & 15;
  const int q = lane >> 4;

  __shared__ float gp[4][BB][35];

  const float* wih = role ? wih6 : wih5;
  const float* whh = role ? whh6 : whh5;
  const float* bih = role ? bih6 : bih5;
  const float* bhh = role ? bhh6 : bhh5;
  unsigned short* hbuf = role ? hbuf6 : hbuf5;
  int* hflags = role ? flags6 : flags5;

  // ---- persistent weight fragments: this wave covers k in [256w, 256w+256)
  // wf[kk*2+nt]: n = 16*nt+ln, k = 256*w + kk*32 + 8*q + j
  short8 wfx[16], wfh[16];
#pragma unroll
  for (int kk = 0; kk < 8; ++kk) {
#pragma unroll
    for (int nt = 0; nt < 2; ++nt) {
      const int n = 16 * nt + ln;
      const int gidx = (n >> 3) * HH + p * 8 + (n & 7); // gate order i,f,g,o
      const int k0 = 256 * w + kk * 32 + 8 * q;
      const float* sx = wih + (size_t)gidx * HH + k0;
      const float* sh = whh + (size_t)gidx * HH + k0;
      short8 vx, vh;
#pragma unroll
      for (int j = 0; j < 8; ++j) { vx[j] = (short)f2bf(sx[j]); vh[j] = (short)f2bf(sh[j]); }
      wfx[kk * 2 + nt] = vx;
      wfh[kk * 2 + nt] = vh;
    }
  }

  // ---- elementwise state: thread owns (b=lane, cols 2w and 2w+1)
  const int eb = lane;
  const int jj0 = w;
  float bsum[2][4];
#pragma unroll
  for (int s = 0; s < 2; ++s) {
    const int jj = 2 * jj0 + s;
#pragma unroll
    for (int gt = 0; gt < 4; ++gt) {
      const int gidx = gt * HH + p * 8 + jj;
      bsum[s][gt] = bih[gidx] + bhh[gidx];
    }
  }
  float cst[2] = {0.f, 0.f};

  // ---- A-operand offsets
  size_t rh[4];  // blocked bf16 layout [t][col>>3][b][col&7]
  size_t rxf[4]; // fp32 row-major [t][b][h] (layer5 x)
#pragma unroll
  for (int mt = 0; mt < 4; ++mt) {
    rh[mt] = (size_t)(16 * mt + ln) * 8 + (size_t)(256 * w + 8 * q) * 64;
    rxf[mt] = (size_t)(16 * mt + ln) * HH + (size_t)(256 * w + 8 * q);
  }

  for (int t = 0; t < TT; ++t) {
    float4v acc[4][2];
#pragma unroll
    for (int mt = 0; mt < 4; ++mt)
#pragma unroll
      for (int nt = 0; nt < 2; ++nt)
        acc[mt][nt] = (float4v){0.f, 0.f, 0.f, 0.f};

    if (role == 0) {
      // ---- layer5 x-part: fp32 x, cvt on the fly (no cross-WG dependency;
      // overlaps other WGs' tails -> VALU hides in straggler slack)
      const float* Xb = x + (size_t)t * BH;
#pragma unroll
      for (int kk = 0; kk < 8; ++kk) {
        short8 af[4];
#pragma unroll
        for (int mt = 0; mt < 4; ++mt) {
          const float* sx = Xb + rxf[mt] + 32 * kk;
          const float4v a = *(const float4v*)sx;
          const float4v b = *(const float4v*)(sx + 4);
          short8 v;
          v[0] = (short)f2bf(a[0]); v[1] = (short)f2bf(a[1]);
          v[2] = (short)f2bf(a[2]); v[3] = (short)f2bf(a[3]);
          v[4] = (short)f2bf(b[0]); v[5] = (short)f2bf(b[1]);
          v[6] = (short)f2bf(b[2]); v[7] = (short)f2bf(b[3]);
          af[mt] = v;
        }
#pragma unroll
        for (int mt = 0; mt < 4; ++mt) {
          acc[mt][0] = __builtin_amdgcn_mfma_f32_16x16x32_bf16(af[mt], wfx[kk * 2 + 0], acc[mt][0], 0, 0, 0);
          acc[mt][1] = __builtin_amdgcn_mfma_f32_16x16x32_bf16(af[mt], wfx[kk * 2 + 1], acc[mt][1], 0, 0, 0);
        }
      }
      // gate h-part on all 128 layer-5 WGs having published h5[t-1]
      if (t > 0) {
        if (w == 0) {
          int* fl = flags5 + (size_t)(t - 1) * GG;
          for (;;) {
            const int a0 = __hip_atomic_load(fl + lane, __ATOMIC_RELAXED, __HIP_MEMORY_SCOPE_AGENT);
            const int a1 = __hip_atomic_load(fl + 64 + lane, __ATOMIC_RELAXED, __HIP_MEMORY_SCOPE_AGENT);
            if (__all((a0 != 0) & (a1 != 0))) break;
            __builtin_amdgcn_s_sleep(2);
          }
        }
        __builtin_amdgcn_fence(__ATOMIC_ACQUIRE, "workgroup"); // compiler order only
        __syncthreads();
      }
    } else {
      // ---- layer6 gate: out5[t] ready (all 128) AND own h6[t-1] ready
      if (w == 0) {
        int* fo = flagsO + (size_t)t * GG;
        int* fh = flags6 + (size_t)(t > 0 ? t - 1 : 0) * GG;
        for (;;) {
          const int a0 = __hip_atomic_load(fo + lane, __ATOMIC_RELAXED, __HIP_MEMORY_SCOPE_AGENT);
          const int a1 = __hip_atomic_load(fo + 64 + lane, __ATOMIC_RELAXED, __HIP_MEMORY_SCOPE_AGENT);
          int ok = (a0 != 0) & (a1 != 0);
          if (t > 0) {
            const int b0 = __hip_atomic_load(fh + lane, __ATOMIC_RELAXED, __HIP_MEMORY_SCOPE_AGENT);
            const int b1 = __hip_atomic_load(fh + 64 + lane, __ATOMIC_RELAXED, __HIP_MEMORY_SCOPE_AGENT);
            ok &= (b0 != 0) & (b1 != 0);
          }
          if (__all(ok)) break;
          __builtin_amdgcn_s_sleep(2);
        }
      }
      __builtin_amdgcn_fence(__ATOMIC_ACQUIRE, "workgroup"); // compiler order only
      __syncthreads();
      // ---- layer6 x-part: out5b blocked bf16 (cached; virgin addrs -> LLC-fresh)
      const unsigned short* Ab = out5b + (size_t)t * BH;
#pragma unroll
      for (int kk = 0; kk < 8; ++kk) {
        short8 af[4];
#pragma unroll
        for (int mt = 0; mt < 4; ++mt)
          af[mt] = *(const short8*)(Ab + rh[mt] + (size_t)kk * 2048);
#pragma unroll
        for (int mt = 0; mt < 4; ++mt) {
          acc[mt][0] = __builtin_amdgcn_mfma_f32_16x16x32_bf16(af[mt], wfx[kk * 2 + 0], acc[mt][0], 0, 0, 0);
          acc[mt][1] = __builtin_amdgcn_mfma_f32_16x16x32_bf16(af[mt], wfx[kk * 2 + 1], acc[mt][1], 0, 0, 0);
        }
      }
    }

    // ---- h-part (common; gating already done per-role above)
    if (t > 0) {
      const unsigned short* Hb = hbuf + (size_t)(t - 1) * BH;
#pragma unroll
      for (int kk = 0; kk < 8; ++kk) {
        short8 af[4];
#pragma unroll
        for (int mt = 0; mt < 4; ++mt)
          af[mt] = *(const short8*)(Hb + rh[mt] + (size_t)kk * 2048); // cached
#pragma unroll
        for (int mt = 0; mt < 4; ++mt) {
          acc[mt][0] = __builtin_amdgcn_mfma_f32_16x16x32_bf16(af[mt], wfh[kk * 2 + 0], acc[mt][0], 0, 0, 0);
          acc[mt][1] = __builtin_amdgcn_mfma_f32_16x16x32_bf16(af[mt], wfh[kk * 2 + 1], acc[mt][1], 0, 0, 0);
        }
      }
    }

    // C layout: row m = 16*mt + 4*q + r, col n = 16*nt + ln
#pragma unroll
    for (int mt = 0; mt < 4; ++mt)
#pragma unroll
      for (int nt = 0; nt < 2; ++nt)
#pragma unroll
        for (int r = 0; r < 4; ++r)
          gp[w][16 * mt + 4 * q + r][16 * nt + ln] = acc[mt][nt][r];

    __syncthreads();

    const size_t tb = (size_t)t * BH;
    const size_t hidx = tb + (size_t)p * 512 + (size_t)eb * 8 + 2 * jj0;
    float hv[2];
#pragma unroll
    for (int s = 0; s < 2; ++s) {
      const int jj = 2 * jj0 + s;
      float iv = bsum[s][0], fv = bsum[s][1], gv = bsum[s][2], ov = bsum[s][3];
#pragma unroll
      for (int ww = 0; ww < 4; ++ww) {
        iv += gp[ww][eb][jj];
        fv += gp[ww][eb][8 + jj];
        gv += gp[ww][eb][16 + jj];
        ov += gp[ww][eb][24 + jj];
      }
      const float ig = sigm(iv);
      const float fg = sigm(fv);
      const float gg_ = tanha(gv);
      const float og = sigm(ov);
      const float c = fg * cst[s] + ig * gg_;
      cst[s] = c;
      hv[s] = og * tanha(c);
    }
    // publish h first: packed 2xbf16 agent-scope 4B store -> LLC
    {
      unsigned packed = (unsigned)f2bf(hv[0]) | ((unsigned)f2bf(hv[1]) << 16);
      __hip_atomic_store((unsigned*)(hbuf + hidx), packed, __ATOMIC_RELAXED,
                         __HIP_MEMORY_SCOPE_AGENT);
    }
    asm volatile("s_waitcnt vmcnt(0)" ::: "memory"); // h store at coherent point
    __syncthreads();
    if (tid == 0)
      __hip_atomic_store(hflags + (size_t)t * GG + p, 1, __ATOMIC_RELAXED,
                         __HIP_MEMORY_SCOPE_AGENT);

    // ---- output tail (phase-separation: this tail keeps the local WG off
    // the fabric while remote pollers' critical h-loads complete)
    if (role == 0) {
      // out5 = h5 + x residual; agent-scope store (cross-XCD visible within
      // this dispatch), then raise flagsO for layer6 consumers.
      const float2v r = *(const float2v*)(x + tb + (size_t)eb * HH + p * 8 + 2 * jj0);
      const float o0 = hv[0] + r[0];
      const float o1 = hv[1] + r[1];
      const unsigned po = (unsigned)f2bf(o0) | ((unsigned)f2bf(o1) << 16);
      __hip_atomic_store((unsigned*)(out5b + hidx), po, __ATOMIC_RELAXED,
                         __HIP_MEMORY_SCOPE_AGENT);
      asm volatile("s_waitcnt vmcnt(0)" ::: "memory");
      __syncthreads();
      if (tid == 0)
        __hip_atomic_store(flagsO + (size_t)t * GG + p, 1, __ATOMIC_RELAXED,
                           __HIP_MEMORY_SCOPE_AGENT);
    } else {
      // final out = h6 + out5 residual (cached read of own cols; virgin->valid)
      const unsigned rb = *(const unsigned*)(out5b + hidx);
      const float o0 = hv[0] + bf2f((unsigned short)(rb & 0xffff));
      const float o1 = hv[1] + bf2f((unsigned short)(rb >> 16));
      float2v vo; vo[0] = o0; vo[1] = o1;
      *(float2v*)(out + tb + (size_t)eb * HH + p * 8 + 2 * jj0) = vo;
    }
  }
}

extern "C" void kernel_launch(void* const* d_in, const int* in_sizes, int n_in,
                              void* d_out, int out_size, void* d_ws, size_t ws_size,
                              hipStream_t stream) {
  const float* x    = (const float*)d_in[0];
  const float* wih5 = (const float*)d_in[1];
  const float* whh5 = (const float*)d_in[2];
  const float* bih5 = (const float*)d_in[3];
  const float* bhh5 = (const float*)d_in[4];
  const float* wih6 = (const float*)d_in[5];
  const float* whh6 = (const float*)d_in[6];
  const float* bih6 = (const float*)d_in[7];
  const float* bhh6 = (const float*)d_in[8];
  float* out = (float*)d_out;

  // ws (96.4 MB):
  //   [0,32M)   out5b : layer5 output bf16 blocked (layer6 x-input + residual)
  //   [32M,64M) hbuf5 : layer5 h history bf16 blocked
  //   [64M,96M) hbuf6 : layer6 h history bf16 blocked
  //   [96M,+384K) flags5 | flagsO | flags6 (TT*GG ints each)
  char* ws = (char*)d_ws;
  unsigned short* out5b = (unsigned short*)(ws);
  unsigned short* hbuf5 = (unsigned short*)(ws + 33554432);
  unsigned short* hbuf6 = (unsigned short*)(ws + 67108864);
  int* flags            = (int*)(ws + 100663296);
  int* flags5 = flags;
  int* flagsO = flags + TT * GG;
  int* flags6 = flags + 2 * TT * GG;

  hipMemsetAsync(flags, 0, 3 * TT * GG * sizeof(int), stream);

  lstm2_fused<<<dim3(2 * GG), dim3(256), 0, stream>>>(
      x, wih5, whh5, bih5, bhh5, wih6, whh6, bih6, bhh6,
      out5b, hbuf5, hbuf6, out, flags5, flagsO, flags6);
}

// Round 7
// 2835.782 us; speedup vs baseline: 1.7568x; 1.2618x over previous
//
#include <hip/hip_runtime.h>

// Residual 2-layer LSTM, T=256 B=64 H=1024, fp32 io, bf16 MFMA compute.
//
// R10 = R9 (fused persistent kernel + XCD-partitioned roles, 3578us) +
// BF16-BLOCKED X VIA ALIASED BUFFER:
//
//  - One-time cvt prologue converts x fp32 row-major -> bf16 BLOCKED
//    [t][h>>3][b][h&7] into `buf` [0,32M). L5's x-part becomes identical to
//    L6's (blocked short8 reads, same rh offsets): halves the per-step x
//    stream through the L5 XCDs' L2s (8MB -> 4MB/XCD/step) and deletes the
//    ~1.1K VALU cvt ops/wave/step from the pre-wait serial segment.
//  - WORKSPACE-NEUTRAL ALIAS: out5b shares `buf` with xb. Safety: xb[t] is
//    dead once all flags5[t] are set (every L5 WG reads x[t] BEFORE its
//    step-t h-wait), and each WG confirms all flags5[t-1] in its step-t
//    h-gate. So the step-t TAIL publishes out5[t-1] (held in po_prev, 1
//    VGPR) into slot t-1. Epilogue (after a flags5[255] wait) publishes
//    out5[255]. L6's flagsO[t] gate therefore fires one L5-step later
//    (~+30us total span, off the recurrence).
//  - Cross-XCD staleness is covered by R9's partition: only XCDs 0-3 cache
//    xb lines (clean); post-overwrite readers (L6) are on XCDs 4-7 and
//    never cached them. Within XCD 0-3, agent-scope stores update/invalidate
//    the local L2 copy, and no L5 WG re-reads slot t-1 after its h-gate.
//
// R4's publish/tail ORDER is preserved shape-for-shape (R5-R7 proved it
// load-bearing): h-publish window (store+drain+barrier+hflag) then tail
// (out5 store+drain+barrier+flagO). Only WHICH step's out5 the tail writes
// changed (t-1 instead of t), plus the rres load moved after the flag.
//
// Coherence (one dispatch, no boundary flush): out5/h5/h6 written with
// AGENT-scope 4B stores + vmcnt(0) drain before their flag. Reader-side
// cached loads are safe per the virgin-address argument + XCD partition.

#define TT 256
#define BB 64
#define HH 1024
#define GG 128
#define BH (BB * HH)

typedef __attribute__((ext_vector_type(8))) short short8;
typedef __attribute__((ext_vector_type(4))) float float4v;
typedef __attribute__((ext_vector_type(2))) float float2v;

__device__ __forceinline__ unsigned short f2bf(float f) {
  unsigned u = __builtin_bit_cast(unsigned, f);
  u += 0x7fffu + ((u >> 16) & 1u);
  return (unsigned short)(u >> 16);
}
__device__ __forceinline__ float bf2f(unsigned short s) {
  unsigned u = ((unsigned)s) << 16;
  return __builtin_bit_cast(float, u);
}
__device__ __forceinline__ float fexp2(float x) { return __builtin_amdgcn_exp2f(x); }
__device__ __forceinline__ float frcp(float x) { return __builtin_amdgcn_rcpf(x); }
__device__ __forceinline__ float sigm(float x) {
  return frcp(1.0f + fexp2(-1.4426950408889634f * x));
}
__device__ __forceinline__ float tanha(float x) {
  return 1.0f - 2.0f * frcp(1.0f + fexp2(2.8853900817779268f * x));
}

// x fp32 [t][b][h] -> bf16 blocked [t][h>>3][b][h&7]. Same f2bf rounding as
// the old on-the-fly cvt -> bit-identical numerics. Writes coalesced (16B
// per lane, b fastest); reads 32B/lane at 4KB stride (L2 absorbs overlap).
__global__ __launch_bounds__(256) void cvt_x_blocked(const float* __restrict__ in,
                                                     unsigned short* __restrict__ out) {
  const int i = blockIdx.x * 256 + threadIdx.x; // [0, TT*BB*HH/8)
  const int t = i >> 13;
  const int r = i & 8191;
  const int c = r >> 6;  // h>>3
  const int b = r & 63;
  const float* src = in + ((size_t)t << 16) + b * 1024 + (c << 3);
  const float4v a = *(const float4v*)src;
  const float4v d = *(const float4v*)(src + 4);
  short8 v;
  v[0] = (short)f2bf(a[0]); v[1] = (short)f2bf(a[1]);
  v[2] = (short)f2bf(a[2]); v[3] = (short)f2bf(a[3]);
  v[4] = (short)f2bf(d[0]); v[5] = (short)f2bf(d[1]);
  v[6] = (short)f2bf(d[2]); v[7] = (short)f2bf(d[3]);
  *(short8*)(out + ((size_t)t << 16) + c * 512 + b * 8) = v;
}

__global__ __launch_bounds__(256, 1) void lstm2_fused(
    const float* __restrict__ x,
    const float* __restrict__ wih5, const float* __restrict__ whh5,
    const float* __restrict__ bih5, const float* __restrict__ bhh5,
    const float* __restrict__ wih6, const float* __restrict__ whh6,
    const float* __restrict__ bih6, const float* __restrict__ bhh6,
    unsigned short* __restrict__ buf, unsigned short* __restrict__ hbuf5,
    unsigned short* __restrict__ hbuf6, float* __restrict__ out,
    int* __restrict__ flags5, int* __restrict__ flagsO,
    int* __restrict__ flags6) {
  // XCD partition (R9): round-robin placement means xcd = bid & 7. L5 ->
  // XCDs 0-3, L6 -> XCDs 4-7; p enumerates [0,128) within each role.
  const int xcd = (int)(blockIdx.x & 7);
  const int role = (xcd >= 4) ? 1 : 0;            // 0 = layer5, 1 = layer6
  const int p = (int)(blockIdx.x >> 3) * 4 + (xcd & 3); // column block (8 h-cols)
  const int tid = threadIdx.x;
  const int w = tid >> 6;
  const int lane = tid & 63;
  const int ln = lane & 15;
  const int q = lane >> 4;

  __shared__ float gp[4][BB][35];

  const float* wih = role ? wih6 : wih5;
  const float* whh = role ? whh6 : whh5;
  const float* bih = role ? bih6 : bih5;
  const float* bhh = role ? bhh6 : bhh5;
  unsigned short* hbuf = role ? hbuf6 : hbuf5;
  int* hflags = role ? flags6 : flags5;

  // ---- persistent weight fragments: this wave covers k in [256w, 256w+256)
  // wf[kk*2+nt]: n = 16*nt+ln, k = 256*w + kk*32 + 8*q + j
  short8 wfx[16], wfh[16];
#pragma unroll
  for (int kk = 0; kk < 8; ++kk) {
#pragma unroll
    for (int nt = 0; nt < 2; ++nt) {
      const int n = 16 * nt + ln;
      const int gidx = (n >> 3) * HH + p * 8 + (n & 7); // gate order i,f,g,o
      const int k0 = 256 * w + kk * 32 + 8 * q;
      const float* sx = wih + (size_t)gidx * HH + k0;
      const float* sh = whh + (size_t)gidx * HH + k0;
      short8 vx, vh;
#pragma unroll
      for (int j = 0; j < 8; ++j) { vx[j] = (short)f2bf(sx[j]); vh[j] = (short)f2bf(sh[j]); }
      wfx[kk * 2 + nt] = vx;
      wfh[kk * 2 + nt] = vh;
    }
  }

  // ---- elementwise state: thread owns (b=lane, cols 2w and 2w+1)
  const int eb = lane;
  const int jj0 = w;
  float bsum[2][4];
#pragma unroll
  for (int s = 0; s < 2; ++s) {
    const int jj = 2 * jj0 + s;
#pragma unroll
    for (int gt = 0; gt < 4; ++gt) {
      const int gidx = gt * HH + p * 8 + jj;
      bsum[s][gt] = bih[gidx] + bhh[gidx];
    }
  }
  float cst[2] = {0.f, 0.f};
  unsigned po_prev = 0; // L5: packed out5 of the PREVIOUS step (deferred publish)

  // ---- A-operand offsets (blocked bf16 layout [t][col>>3][b][col&7];
  // both roles' x-parts and h-parts now share this addressing)
  size_t rh[4];
#pragma unroll
  for (int mt = 0; mt < 4; ++mt)
    rh[mt] = (size_t)(16 * mt + ln) * 8 + (size_t)(256 * w + 8 * q) * 64;

  for (int t = 0; t < TT; ++t) {
    float4v acc[4][2];
#pragma unroll
    for (int mt = 0; mt < 4; ++mt)
#pragma unroll
      for (int nt = 0; nt < 2; ++nt)
        acc[mt][nt] = (float4v){0.f, 0.f, 0.f, 0.f};

    if (role == 0) {
      // ---- layer5 x-part: blocked bf16 x from buf (cvt prologue; slot t is
      // pristine xb -- out5 overwrites slot t only at step t+1, after all
      // flags5[t] confirmed every L5 WG finished reading it)
      const unsigned short* Ab = buf + (size_t)t * BH;
#pragma unroll
      for (int kk = 0; kk < 8; ++kk) {
        short8 af[4];
#pragma unroll
        for (int mt = 0; mt < 4; ++mt)
          af[mt] = *(const short8*)(Ab + rh[mt] + (size_t)kk * 2048);
#pragma unroll
        for (int mt = 0; mt < 4; ++mt) {
          acc[mt][0] = __builtin_amdgcn_mfma_f32_16x16x32_bf16(af[mt], wfx[kk * 2 + 0], acc[mt][0], 0, 0, 0);
          acc[mt][1] = __builtin_amdgcn_mfma_f32_16x16x32_bf16(af[mt], wfx[kk * 2 + 1], acc[mt][1], 0, 0, 0);
        }
      }
      // gate h-part on all 128 layer-5 WGs having published h5[t-1]
      if (t > 0) {
        if (w == 0) {
          int* fl = flags5 + (size_t)(t - 1) * GG;
          for (;;) {
            const int a0 = __hip_atomic_load(fl + lane, __ATOMIC_RELAXED, __HIP_MEMORY_SCOPE_AGENT);
            const int a1 = __hip_atomic_load(fl + 64 + lane, __ATOMIC_RELAXED, __HIP_MEMORY_SCOPE_AGENT);
            if (__all((a0 != 0) & (a1 != 0))) break;
            __builtin_amdgcn_s_sleep(2);
          }
        }
        __builtin_amdgcn_fence(__ATOMIC_ACQUIRE, "workgroup"); // compiler order only
        __syncthreads();
      }
    } else {
      // ---- layer6 gate: out5[t] ready (all 128; flagsO[t] is raised in
      // L5's step-t+1 tail / epilogue) AND own h6[t-1] ready
      if (w == 0) {
        int* fo = flagsO + (size_t)t * GG;
        int* fh = flags6 + (size_t)(t > 0 ? t - 1 : 0) * GG;
        for (;;) {
          const int a0 = __hip_atomic_load(fo + lane, __ATOMIC_RELAXED, __HIP_MEMORY_SCOPE_AGENT);
          const int a1 = __hip_atomic_load(fo + 64 + lane, __ATOMIC_RELAXED, __HIP_MEMORY_SCOPE_AGENT);
          int ok = (a0 != 0) & (a1 != 0);
          if (t > 0) {
            const int b0 = __hip_atomic_load(fh + lane, __ATOMIC_RELAXED, __HIP_MEMORY_SCOPE_AGENT);
            const int b1 = __hip_atomic_load(fh + 64 + lane, __ATOMIC_RELAXED, __HIP_MEMORY_SCOPE_AGENT);
            ok &= (b0 != 0) & (b1 != 0);
          }
          if (__all(ok)) break;
          __builtin_amdgcn_s_sleep(2);
        }
      }
      __builtin_amdgcn_fence(__ATOMIC_ACQUIRE, "workgroup"); // compiler order only
      __syncthreads();
      // ---- layer6 x-part: out5 blocked bf16 from buf (cached; XCDs 4-7
      // never held these lines pre-write -> LLC-fresh)
      const unsigned short* Ab = buf + (size_t)t * BH;
#pragma unroll
      for (int kk = 0; kk < 8; ++kk) {
        short8 af[4];
#pragma unroll
        for (int mt = 0; mt < 4; ++mt)
          af[mt] = *(const short8*)(Ab + rh[mt] + (size_t)kk * 2048);
#pragma unroll
        for (int mt = 0; mt < 4; ++mt) {
          acc[mt][0] = __builtin_amdgcn_mfma_f32_16x16x32_bf16(af[mt], wfx[kk * 2 + 0], acc[mt][0], 0, 0, 0);
          acc[mt][1] = __builtin_amdgcn_mfma_f32_16x16x32_bf16(af[mt], wfx[kk * 2 + 1], acc[mt][1], 0, 0, 0);
        }
      }
    }

    // ---- h-part (common; gating already done per-role above)
    if (t > 0) {
      const unsigned short* Hb = hbuf + (size_t)(t - 1) * BH;
#pragma unroll
      for (int kk = 0; kk < 8; ++kk) {
        short8 af[4];
#pragma unroll
        for (int mt = 0; mt < 4; ++mt)
          af[mt] = *(const short8*)(Hb + rh[mt] + (size_t)kk * 2048); // cached
#pragma unroll
        for (int mt = 0; mt < 4; ++mt) {
          acc[mt][0] = __builtin_amdgcn_mfma_f32_16x16x32_bf16(af[mt], wfh[kk * 2 + 0], acc[mt][0], 0, 0, 0);
          acc[mt][1] = __builtin_amdgcn_mfma_f32_16x16x32_bf16(af[mt], wfh[kk * 2 + 1], acc[mt][1], 0, 0, 0);
        }
      }
    }

    // C layout: row m = 16*mt + 4*q + r, col n = 16*nt + ln
#pragma unroll
    for (int mt = 0; mt < 4; ++mt)
#pragma unroll
      for (int nt = 0; nt < 2; ++nt)
#pragma unroll
        for (int r = 0; r < 4; ++r)
          gp[w][16 * mt + 4 * q + r][16 * nt + ln] = acc[mt][nt][r];

    __syncthreads();

    const size_t tb = (size_t)t * BH;
    const size_t hidx = tb + (size_t)p * 512 + (size_t)eb * 8 + 2 * jj0;
    float hv[2];
#pragma unroll
    for (int s = 0; s < 2; ++s) {
      const int jj = 2 * jj0 + s;
      float iv = bsum[s][0], fv = bsum[s][1], gv = bsum[s][2], ov = bsum[s][3];
#pragma unroll
      for (int ww = 0; ww < 4; ++ww) {
        iv += gp[ww][eb][jj];
        fv += gp[ww][eb][8 + jj];
        gv += gp[ww][eb][16 + jj];
        ov += gp[ww][eb][24 + jj];
      }
      const float ig = sigm(iv);
      const float fg = sigm(fv);
      const float gg_ = tanha(gv);
      const float og = sigm(ov);
      const float c = fg * cst[s] + ig * gg_;
      cst[s] = c;
      hv[s] = og * tanha(c);
    }
    // publish h first: packed 2xbf16 agent-scope 4B store -> LLC
    {
      unsigned packed = (unsigned)f2bf(hv[0]) | ((unsigned)f2bf(hv[1]) << 16);
      __hip_atomic_store((unsigned*)(hbuf + hidx), packed, __ATOMIC_RELAXED,
                         __HIP_MEMORY_SCOPE_AGENT);
    }
    asm volatile("s_waitcnt vmcnt(0)" ::: "memory"); // h store at coherent point
    __syncthreads();
    if (tid == 0)
      __hip_atomic_store(hflags + (size_t)t * GG + p, 1, __ATOMIC_RELAXED,
                         __HIP_MEMORY_SCOPE_AGENT);

    // ---- output tail (phase-separation: keeps the local WG's fabric quiet
    // window while remote pollers' critical h-loads complete)
    if (role == 0) {
      if (t > 0) {
        // deferred publish: out5[t-1] into buf slot t-1 (safe -- this step's
        // h-gate confirmed all flags5[t-1], so every L5 WG has finished
        // reading slot t-1 as x)
        __hip_atomic_store((unsigned*)(buf + (hidx - BH)), po_prev, __ATOMIC_RELAXED,
                           __HIP_MEMORY_SCOPE_AGENT);
        asm volatile("s_waitcnt vmcnt(0)" ::: "memory");
        __syncthreads();
        if (tid == 0)
          __hip_atomic_store(flagsO + (size_t)(t - 1) * GG + p, 1, __ATOMIC_RELAXED,
                             __HIP_MEMORY_SCOPE_AGENT);
      }
      // prepare next step's deferred value: out5[t] = h5[t] + x residual
      const float2v r = *(const float2v*)(x + tb + (size_t)eb * HH + p * 8 + 2 * jj0);
      const float o0 = hv[0] + r[0];
      const float o1 = hv[1] + r[1];
      po_prev = (unsigned)f2bf(o0) | ((unsigned)f2bf(o1) << 16);
    } else {
      // final out = h6 + out5 residual (cached read of own cols; published
      // under flagsO[t] which this WG confirmed before its x-part)
      const unsigned rb = *(const unsigned*)(buf + hidx);
      const float o0 = hv[0] + bf2f((unsigned short)(rb & 0xffff));
      const float o1 = hv[1] + bf2f((unsigned short)(rb >> 16));
      float2v vo; vo[0] = o0; vo[1] = o1;
      *(float2v*)(out + tb + (size_t)eb * HH + p * 8 + 2 * jj0) = vo;
    }
  }

  // ---- L5 epilogue: publish out5[TT-1] once all flags5[TT-1] are set
  // (i.e. every L5 WG finished reading slot TT-1 as x)
  if (role == 0) {
    if (w == 0) {
      int* fl = flags5 + (size_t)(TT - 1) * GG;
      for (;;) {
        const int a0 = __hip_atomic_load(fl + lane, __ATOMIC_RELAXED, __HIP_MEMORY_SCOPE_AGENT);
        const int a1 = __hip_atomic_load(fl + 64 + lane, __ATOMIC_RELAXED, __HIP_MEMORY_SCOPE_AGENT);
        if (__all((a0 != 0) & (a1 != 0))) break;
        __builtin_amdgcn_s_sleep(2);
      }
    }
    __builtin_amdgcn_fence(__ATOMIC_ACQUIRE, "workgroup");
    __syncthreads();
    const size_t hlast = (size_t)(TT - 1) * BH + (size_t)p * 512 + (size_t)eb * 8 + 2 * jj0;
    __hip_atomic_store((unsigned*)(buf + hlast), po_prev, __ATOMIC_RELAXED,
                       __HIP_MEMORY_SCOPE_AGENT);
    asm volatile("s_waitcnt vmcnt(0)" ::: "memory");
    __syncthreads();
    if (tid == 0)
      __hip_atomic_store(flagsO + (size_t)(TT - 1) * GG + p, 1, __ATOMIC_RELAXED,
                         __HIP_MEMORY_SCOPE_AGENT);
  }
}

extern "C" void kernel_launch(void* const* d_in, const int* in_sizes, int n_in,
                              void* d_out, int out_size, void* d_ws, size_t ws_size,
                              hipStream_t stream) {
  const float* x    = (const float*)d_in[0];
  const float* wih5 = (const float*)d_in[1];
  const float* whh5 = (const float*)d_in[2];
  const float* bih5 = (const float*)d_in[3];
  const float* bhh5 = (const float*)d_in[4];
  const float* wih6 = (const float*)d_in[5];
  const float* whh6 = (const float*)d_in[6];
  const float* bih6 = (const float*)d_in[7];
  const float* bhh6 = (const float*)d_in[8];
  float* out = (float*)d_out;

  // ws (96.4 MB):
  //   [0,32M)   buf   : x bf16 blocked, ALIASED with layer5 output (out5);
  //                     slot t flips xb->out5 at L5 step t+1 (proven-dead)
  //   [32M,64M) hbuf5 : layer5 h history bf16 blocked
  //   [64M,96M) hbuf6 : layer6 h history bf16 blocked
  //   [96M,+384K) flags5 | flagsO | flags6 (TT*GG ints each)
  char* ws = (char*)d_ws;
  unsigned short* buf   = (unsigned short*)(ws);
  unsigned short* hbuf5 = (unsigned short*)(ws + 33554432);
  unsigned short* hbuf6 = (unsigned short*)(ws + 67108864);
  int* flags            = (int*)(ws + 100663296);
  int* flags5 = flags;
  int* flagsO = flags + TT * GG;
  int* flags6 = flags + 2 * TT * GG;

  hipMemsetAsync(flags, 0, 3 * TT * GG * sizeof(int), stream);

  cvt_x_blocked<<<dim3(TT * BB * HH / 8 / 256), dim3(256), 0, stream>>>(x, buf);

  lstm2_fused<<<dim3(2 * GG), dim3(256), 0, stream>>>(
      x, wih5, whh5, bih5, bhh5, wih6, whh6, bih6, bhh6,
      buf, hbuf5, hbuf6, out, flags5, flagsO, flags6);
}